// Round 9
// baseline (318.386 us; speedup 1.0000x reference)
//
#include <hip/hip_runtime.h>

// ---------------------------------------------------------------------------
// TextGCN (2-layer GCN, eval mode) on MI355X.
// Fusions:
//   * xw1_word = word @ (W_lin@W1) + (b_lin@W1)  (never materialize [N,768] x)
//   * layer 2: agg(h1@W2)[mask] == agg(h1)[mask] @ W2
// CSR BUILD = 2-LEVEL BUCKET SORT (no scattered-megaop atomics, r3 measured).
// GEMM: 16 rows/wave, CHUNK-deep A-load hoist, B always packed bf16 (r5/r6).
// CHAIN SURGERY (r8): all kernels < 56us; loss = launches + serialization.
//   * fuse GEMM epilogue writes packWf bf16 FRAGMENTS directly (+ bfuse fp32
//     row 300) -- closed-form (r,c)->frag-index map; WfuseB + repack deleted.
//   * k_scanB deleted: scatter/build blocks redundantly compute the bucket
//     prefix-scan in LDS (pair-load + 256-wide scan over <=512 buckets);
//     scatter reserves runs via local base + atomicAdd(runInc) (runInc
//     zeroed in k_pack).
//   * k_agg2m + k_mfma_final fused into k_out: 16 masked rows gathered to
//     LDS [16][65] (2-way banks, free), wave 0 projects @W2 -> d_out.
//     tmask round-trip deleted.
// PIPELINE (6 launches, 0 memsets):
//   k_pack(packW1||packW2||zero{bucketTot,runInc,packWf tail}) ->
//   k_pre(bucketHist || fuseGEMM->packWf,bfuse || docGEMM) ->
//   k_sd(scatter+scan || wordGEMM rows[0,half)) ->
//   k_bw(bucketBuild+scan || wordGEMM rows[half,NW)) ->
//   k_agg -> k_out(masked agg + @W2 projection)
// xw1/h1 bf16 in PERMUTED column order pi(pos)=(pos&3)*16+(pos>>2) (coalesced
// 8B MFMA epilogue stores). b1 indexed via pi; packW2 k-rows permuted via pi.
// ebuf record: {src | (dst&255)<<17, w}  (src < 2^17 since N <= 131072).
// Fixed cost: harness re-poisons 384MB ws (~56us/iter @85% HBM peak).
// ---------------------------------------------------------------------------

typedef __attribute__((ext_vector_type(8))) short short8;   // 8 bf16 = 4 VGPR
typedef __attribute__((ext_vector_type(4))) float float4v;  // MFMA C/D frag

__device__ __forceinline__ unsigned short f2bf(float f) {   // RNE f32->bf16
  unsigned u = __float_as_uint(f);
  return (unsigned short)((u + 0x7FFFu + ((u >> 16) & 1u)) >> 16);
}
__device__ __forceinline__ float bf2f(unsigned short u) {
  return __uint_as_float((unsigned)u << 16);
}
__device__ __forceinline__ int permcol(int p) {   // pi: pos -> true col
  return ((p & 3) << 4) | (p >> 2);
}

// pack W[K,64] fp32 -> bf16 fragment order: pack[((g*nk0+k0)*64+lane)*8+j]
// holds W[ksrc][(lane&15)+16g], ksrc = PERM ? pi(k) : k; zero past K.
template <bool PERM>
__device__ __forceinline__ void pack_w_body(const float* __restrict__ W, int K,
                                            int nk0, unsigned short* __restrict__ pack,
                                            int tid) {
  int lane = tid & 63;
  int rest = tid >> 6;
  int k0 = rest % nk0;
  int g = rest / nk0;
  int quad = lane >> 4;
  int n = (lane & 15) + g * 16;
  short8 v;
#pragma unroll
  for (int j = 0; j < 8; ++j) {
    int k = k0 * 32 + quad * 8 + j;
    int ks = PERM ? permcol(k) : k;
    float w = (k < K) ? W[(size_t)ks * 64 + n] : 0.f;
    v[j] = (short)f2bf(w);
  }
  *(short8*)(pack + (((size_t)(g * nk0 + k0) * 64 + lane) << 3)) = v;
}

// MFMA GEMM: out[R,64] = X[R,K(ldx)] @ W[K,64] (+bias). One wave = 16 rows.
// NK0/CHUNK compile-time: A-loads for CHUNK k0s issued back-to-back (deep
// MLP), then convert+MFMA. B from packed bf16 fragments (L2-hot).
// FUSEOUT: epilogue writes packWf fragments (nk0=10 layout, rows<300) and
// bfuseOut fp32 (row 300) instead of a normal output matrix.
template <bool LAST, bool BF16PERM, bool FUSEOUT, int NK0, int CHUNK>
__device__ __forceinline__ void mfma_gemm_body(
    const float* __restrict__ X, int ldx, const float* __restrict__ lastRow,
    const unsigned short* __restrict__ Wpack,
    int K, const float* __restrict__ bias,
    void* __restrict__ outv, int R, int waveIdx, float* __restrict__ bfuseOut) {
  int r0 = waveIdx * 16;
  if (r0 >= R) return;
  const int lane = threadIdx.x & 63;
  const int quad = lane >> 4;
  const int m = lane & 15;
  const float* xrow = nullptr;
  {
    int row = r0 + m;
    if (row < R) xrow = (LAST && row == R - 1) ? lastRow : X + (size_t)row * ldx;
  }

  float4v acc[4];
#pragma unroll
  for (int g = 0; g < 4; ++g) acc[g] = (float4v){0.f, 0.f, 0.f, 0.f};

#pragma unroll
  for (int c0 = 0; c0 < NK0; c0 += CHUNK) {
    // ---- A-hoist: all CHUNK k0 loads, no dependent compute between ----
    float a[CHUNK][8];
#pragma unroll
    for (int cc = 0; cc < CHUNK; ++cc) {
      int kb = (c0 + cc) * 32 + quad * 8;
      if (xrow && kb + 8 <= K) {
        float4 v0 = *(const float4*)(xrow + kb);
        float4 v1 = *(const float4*)(xrow + kb + 4);
        a[cc][0] = v0.x; a[cc][1] = v0.y; a[cc][2] = v0.z; a[cc][3] = v0.w;
        a[cc][4] = v1.x; a[cc][5] = v1.y; a[cc][6] = v1.z; a[cc][7] = v1.w;
      } else {
#pragma unroll
        for (int j = 0; j < 8; ++j) {
          int k = kb + j;
          a[cc][j] = (xrow && k < K) ? xrow[k] : 0.f;
        }
      }
    }
    // ---- compute the chunk (packed bf16 B fragments) ----
#pragma unroll
    for (int cc = 0; cc < CHUNK; ++cc) {
      int k0 = c0 + cc;
      short8 bf[4];
#pragma unroll
      for (int g = 0; g < 4; ++g)
        bf[g] = *(const short8*)(Wpack + (((size_t)(g * NK0 + k0) * 64 + lane) << 3));
      short8 af;
#pragma unroll
      for (int j = 0; j < 8; ++j) af[j] = (short)f2bf(a[cc][j]);
#pragma unroll
      for (int g = 0; g < 4; ++g)
        acc[g] = __builtin_amdgcn_mfma_f32_16x16x32_bf16(af, bf[g], acc[g], 0, 0, 0);
    }
  }

  // ---- epilogue ----
  if (FUSEOUT) {
    // write packWf fragments (nk0=10): element (k=r, n=c) ->
    // pack[((g*10 + r/32)*64 + ((r%32)/8)*16 + m)*8 + r%8]
    unsigned short* pf = (unsigned short*)outv;
#pragma unroll
    for (int g = 0; g < 4; ++g) {
#pragma unroll
      for (int reg = 0; reg < 4; ++reg) {
        int r = r0 + quad * 4 + reg;
        if (r < 300) {
          size_t idx = ((((size_t)(g * 10 + (r >> 5))) * 64 + (((r >> 3) & 3) << 4) + m) << 3)
                       + (r & 7);
          pf[idx] = f2bf(acc[g][reg]);
        } else if (r == 300) {
          bfuseOut[g * 16 + m] = acc[g][reg];
        }
      }
    }
  } else if (BF16PERM) {
    // lane m packs cols {m,16+m,32+m,48+m} of row r0+quad*4+j as 4 bf16 (8B)
    float b0 = bias ? bias[m] : 0.f;
    float b1 = bias ? bias[16 + m] : 0.f;
    float b2 = bias ? bias[32 + m] : 0.f;
    float b3 = bias ? bias[48 + m] : 0.f;
#pragma unroll
    for (int j = 0; j < 4; ++j) {
      int r = r0 + quad * 4 + j;
      if (r < R) {
        ushort4 pk;
        pk.x = f2bf(acc[0][j] + b0);
        pk.y = f2bf(acc[1][j] + b1);
        pk.z = f2bf(acc[2][j] + b2);
        pk.w = f2bf(acc[3][j] + b3);
        *(ushort4*)((unsigned short*)outv + ((size_t)r * 64 + m * 4)) = pk;
      }
    }
  } else {
#pragma unroll
    for (int g = 0; g < 4; ++g) {
      float b = bias ? bias[g * 16 + m] : 0.f;
#pragma unroll
      for (int reg = 0; reg < 4; ++reg) {
        int r = r0 + quad * 4 + reg;   // C/D: col=lane&15, row=quad*4+reg
        if (r < R) ((float*)outv)[(size_t)r * 64 + g * 16 + m] = acc[g][reg] + b;
      }
    }
  }
}

// k_pack: [24) pack W1; [+2) pack W2 (permuted k);
//         [+1) zero bucketTot + runInc + packWf k0=9 tail (k=288..319).
__global__ __launch_bounds__(256) void k_pack(
    const float* __restrict__ W1, unsigned short* __restrict__ packW1,
    const float* __restrict__ W2, unsigned short* __restrict__ packW2,
    int* __restrict__ bucketTot, int* __restrict__ runInc, int nbuck,
    unsigned short* __restrict__ packWf) {
  int b = blockIdx.x;
  int t = threadIdx.x;
  if (b < 24) { pack_w_body<false>(W1, 768, 24, packW1, b * 256 + t); return; }
  b -= 24;
  if (b < 2) { pack_w_body<true>(W2, 64, 2, packW2, b * 256 + t); return; }
  for (int i = t; i < nbuck + 2; i += 256) { bucketTot[i] = 0; runInc[i] = 0; }
  // zero packWf k0=9 fragments (fuse epilogue fills k=288..299; 300..319 = 0)
  int g = t >> 6, lane = t & 63;
  *(short8*)(packWf + (((size_t)(g * 10 + 9) * 64 + lane) << 3)) = (short8){0,0,0,0,0,0,0,0};
}

// k_pre: [histBlocks) bucket histogram (LDS, flush <=nbuck atomics/block);
//        [+fuseBlocks) fuse GEMM [Wlin;blin]@W1 -> packWf + bfuse (FUSEOUT);
//        rest: doc GEMM (packed W1) -> xw1 rows [0,ND).
__global__ __launch_bounds__(256) void k_pre(
    const float* __restrict__ Wlin, const float* __restrict__ blin,
    const unsigned short* __restrict__ packW1,
    unsigned short* __restrict__ packWf, float* __restrict__ bfuse,
    int histBlocks, int fuseBlocks,
    const int* __restrict__ ei, int E, int* __restrict__ bucketTot, int nbuck,
    const float* __restrict__ doc, unsigned short* __restrict__ xw1, int ND) {
  int b = blockIdx.x;
  int t = threadIdx.x;
  if (b < histBlocks) {
    __shared__ int h[512];
    h[t] = 0; h[t + 256] = 0;
    __syncthreads();
    int e0 = b * 4096;
#pragma unroll 4
    for (int i = 0; i < 16; ++i) {
      int e = e0 + t + i * 256;
      if (e < E) atomicAdd(&h[ei[E + e] >> 8], 1);
    }
    __syncthreads();
    if (t < nbuck && h[t]) atomicAdd(bucketTot + t, h[t]);
    if (t + 256 < nbuck && h[t + 256]) atomicAdd(bucketTot + t + 256, h[t + 256]);
    return;
  }
  b -= histBlocks;
  if (b < fuseBlocks) {
    mfma_gemm_body<true, false, true, 24, 8>(Wlin, 768, blin, packW1, 768,
                                             nullptr, packWf, 301, b * 4 + (t >> 6), bfuse);
    return;
  }
  b -= fuseBlocks;
  mfma_gemm_body<false, true, false, 24, 8>(doc, 768, nullptr, packW1, 768,
                                            nullptr, xw1, ND, b * 4 + (t >> 6), nullptr);
}

// in-block bucket prefix scan: bb[0..512] exclusive bases from bucketTot.
// 256 threads, pair-load + Hillis-Steele. Caller provides LDS arrays.
__device__ __forceinline__ void bucket_scan(const int* __restrict__ bucketTot, int nbuck,
                                            int* __restrict__ sc, int* __restrict__ bb,
                                            int t) {
  int a0 = (2 * t < nbuck) ? bucketTot[2 * t] : 0;
  int a1 = (2 * t + 1 < nbuck) ? bucketTot[2 * t + 1] : 0;
  sc[t] = a0 + a1;
  __syncthreads();
  for (int off = 1; off < 256; off <<= 1) {
    int x = (t >= off) ? sc[t - off] : 0;
    __syncthreads();
    sc[t] += x;
    __syncthreads();
  }
  int pe = sc[t] - a0 - a1;
  bb[2 * t] = pe;
  bb[2 * t + 1] = pe + a0;
  if (t == 255) bb[512] = sc[255];
  __syncthreads();
}

// k_sd: [scatBlocks) scatter edges into bucket-grouped ebuf (LDS hist+rank,
// run reservation = local bucket base + atomicAdd(runInc)); rest: word GEMM
// rows [0, NWsd) (packed WfuseB fragments).
__global__ __launch_bounds__(256) void k_sd(
    const int* __restrict__ ei, const float* __restrict__ ew, int E,
    int scatBlocks, const int* __restrict__ bucketTot, int nbuck,
    int* __restrict__ runInc, int2* __restrict__ ebuf,
    const float* __restrict__ wordf, const unsigned short* __restrict__ packWf,
    const float* __restrict__ bfuse, unsigned short* __restrict__ xw1word, int NWsd) {
  int b = blockIdx.x;
  int t = threadIdx.x;
  if (b >= scatBlocks) {
    mfma_gemm_body<false, true, false, 10, 5>(wordf, 300, nullptr, packWf, 300,
                                              bfuse, xw1word, NWsd,
                                              (b - scatBlocks) * 4 + (t >> 6), nullptr);
    return;
  }
  __shared__ int h[512];
  __shared__ int base[512];
  __shared__ int cur[512];
  __shared__ int bb[513];
  __shared__ int sc[256];
  h[t] = 0; h[t + 256] = 0;
  __syncthreads();
  int e0 = b * 4096;
#pragma unroll 4
  for (int i = 0; i < 16; ++i) {
    int e = e0 + t + i * 256;
    if (e < E) atomicAdd(&h[ei[E + e] >> 8], 1);
  }
  __syncthreads();
  bucket_scan(bucketTot, nbuck, sc, bb, t);   // also covers hist completion
#pragma unroll
  for (int k = t; k < 512; k += 256) {
    if (h[k]) base[k] = bb[k] + atomicAdd(runInc + k, h[k]);
    cur[k] = 0;
  }
  __syncthreads();
#pragma unroll 4
  for (int i = 0; i < 16; ++i) {
    int e = e0 + t + i * 256;
    if (e < E) {
      int d = ei[E + e];
      int bk = d >> 8;
      int r = base[bk] + atomicAdd(&cur[bk], 1);
      ebuf[r] = make_int2(ei[e] | ((d & 255) << 17), __float_as_int(ew[e]));
    }
  }
}

// k_bw: [nbuck) per-bucket CSR build (local scan -> estart/eend; LDS
// cnt/wdeg/scan -> contiguous entries slice + offs + dis); rest: word GEMM
// rows [NWsd, NW) via pre-offset pointers.
__global__ __launch_bounds__(256) void k_bw(
    const int2* __restrict__ ebuf, const int* __restrict__ bucketTot,
    int nbuck, int N, int* __restrict__ offs, float* __restrict__ dis,
    int2* __restrict__ entries,
    const float* __restrict__ wordf2, const unsigned short* __restrict__ packWf,
    const float* __restrict__ bfuse, unsigned short* __restrict__ xw1word2, int NW2) {
  int b = blockIdx.x;
  int t = threadIdx.x;
  if (b >= nbuck) {
    mfma_gemm_body<false, true, false, 10, 5>(wordf2, 300, nullptr, packWf, 300,
                                              bfuse, xw1word2, NW2,
                                              (b - nbuck) * 4 + (t >> 6), nullptr);
    return;
  }
  __shared__ int scnt[256];
  __shared__ float swd[256];
  __shared__ int sscan[256];
  __shared__ int scur[256];
  __shared__ int bb[513];
  __shared__ int sc[256];
  bucket_scan(bucketTot, nbuck, sc, bb, t);
  int estart = bb[b], eend = bb[b + 1];
  int node0 = b << 8;
  int nn = min(256, N - node0);
  scnt[t] = (t < nn) ? 1 : 0;          // self loop
  swd[t] = (t < nn) ? 1.f : 0.f;       // self weight
  __syncthreads();
  for (int p = estart + t; p < eend; p += 256) {
    int2 e = ebuf[p];
    int low = (e.x >> 17) & 255;
    atomicAdd(&scnt[low], 1);
    atomicAdd(&swd[low], __int_as_float(e.y));
  }
  __syncthreads();
  int v = scnt[t];
  sscan[t] = v; __syncthreads();
  for (int off = 1; off < 256; off <<= 1) {
    int x = (t >= off) ? sscan[t - off] : 0;
    __syncthreads();
    sscan[t] += x;
    __syncthreads();
  }
  int excl = sscan[t] - v;
  int entriesBase = estart + node0;    // edges-before + selfs-before
  if (t < nn) {
    offs[node0 + t] = entriesBase + excl;
    dis[node0 + t] = rsqrtf(fmaxf(swd[t], 1e-12f));
    entries[entriesBase + excl] = make_int2(node0 + t, __float_as_int(1.0f));
  }
  scur[t] = excl + 1;
  if (t == 0 && b == nbuck - 1) offs[N] = entriesBase + (eend - estart) + nn;
  __syncthreads();
  for (int p = estart + t; p < eend; p += 256) {
    int2 e = ebuf[p];
    int low = (e.x >> 17) & 255;
    int r = atomicAdd(&scur[low], 1);
    entries[entriesBase + r] = make_int2(e.x & 0x1FFFF, e.y);
  }
}

// half-wave gather-accumulate: 32 lanes, each lane covers 2 cols (ushort2).
// entries hold RAW w -> multiply dis[src] per entry (broadcast, L2-hot).
__device__ __forceinline__ void row_gather2(const unsigned short* __restrict__ xin,
                                            const int2* __restrict__ entries,
                                            const float* __restrict__ dis,
                                            int p, int pe, int l32,
                                            float& ra0, float& ra1) {
  float a0 = 0.f, a1 = 0.f;
  for (; p + 8 <= pe; p += 8) {
    int2 e[8];
#pragma unroll
    for (int j = 0; j < 8; ++j) e[j] = entries[p + j];
    unsigned x[8];
    float ds[8];
#pragma unroll
    for (int j = 0; j < 8; ++j) {
      x[j] = *(const unsigned*)(xin + ((size_t)e[j].x << 6) + (l32 << 1));
      ds[j] = dis[e[j].x];
    }
#pragma unroll
    for (int j = 0; j < 8; ++j) {
      float w = __int_as_float(e[j].y) * ds[j];
      a0 = fmaf(bf2f((unsigned short)(x[j] & 0xffffu)), w, a0);
      a1 = fmaf(bf2f((unsigned short)(x[j] >> 16)), w, a1);
    }
  }
  if (p + 4 <= pe) {
    int2 e[4];
#pragma unroll
    for (int j = 0; j < 4; ++j) e[j] = entries[p + j];
    unsigned x[4];
    float ds[4];
#pragma unroll
    for (int j = 0; j < 4; ++j) {
      x[j] = *(const unsigned*)(xin + ((size_t)e[j].x << 6) + (l32 << 1));
      ds[j] = dis[e[j].x];
    }
#pragma unroll
    for (int j = 0; j < 4; ++j) {
      float w = __int_as_float(e[j].y) * ds[j];
      a0 = fmaf(bf2f((unsigned short)(x[j] & 0xffffu)), w, a0);
      a1 = fmaf(bf2f((unsigned short)(x[j] >> 16)), w, a1);
    }
    p += 4;
  }
  for (; p < pe; ++p) {
    int2 e = entries[p];
    unsigned x = *(const unsigned*)(xin + ((size_t)e.x << 6) + (l32 << 1));
    float w = __int_as_float(e.y) * dis[e.x];
    a0 = fmaf(bf2f((unsigned short)(x & 0xffffu)), w, a0);
    a1 = fmaf(bf2f((unsigned short)(x >> 16)), w, a1);
  }
  ra0 = a0; ra1 = a1;
}

// layer-1 aggregation: half-wave per node, ushort2 out (permuted pos layout)
__global__ void k_agg(const unsigned short* __restrict__ xin, const int2* __restrict__ entries,
                      const int* __restrict__ offs, const float* __restrict__ dis,
                      const float* __restrict__ bias, unsigned short* __restrict__ xout, int N) {
  const int tid = threadIdx.x;
  const int l32 = tid & 31;
  int i = blockIdx.x * 8 + (tid >> 5);
  if (i >= N) return;
  float a0, a1;
  row_gather2(xin, entries, dis, offs[i], offs[i + 1], l32, a0, a1);
  float d = dis[i];
  a0 = fmaxf(fmaf(a0, d, bias[permcol(2 * l32)]), 0.f);
  a1 = fmaxf(fmaf(a1, d, bias[permcol(2 * l32 + 1)]), 0.f);
  ushort2 pk;
  pk.x = f2bf(a0);
  pk.y = f2bf(a1);
  *(ushort2*)(xout + ((size_t)i << 6) + (l32 << 1)) = pk;
}

// k_out: fused masked layer-2 aggregation + [16,64]@[64,64]+b2 projection.
// Block = 16 masked nodes: 8 half-waves x 2 rounds gather into LDS rows
// (pos order, pad 65 -> 2-way banks = free), then wave 0 MFMAs with
// permuted-k packW2 and writes fp32 out. outY written during gather.
__global__ __launch_bounds__(256) void k_out(
    const unsigned short* __restrict__ h1, const int2* __restrict__ entries,
    const int* __restrict__ offs, const float* __restrict__ dis,
    const int* __restrict__ mask, const int* __restrict__ y,
    const unsigned short* __restrict__ packW2, const float* __restrict__ b2,
    float* __restrict__ out0, float* __restrict__ outY, int M) {
  __shared__ float rows[16][65];
  const int t = threadIdx.x;
  const int l32 = t & 31;
  const int hw = t >> 5;
  const int ob = blockIdx.x * 16;
#pragma unroll
  for (int rd = 0; rd < 2; ++rd) {
    int r = rd * 8 + hw;
    int o = ob + r;
    float a0 = 0.f, a1 = 0.f;
    if (o < M) {
      int i = mask[o];
      row_gather2(h1, entries, dis, offs[i], offs[i + 1], l32, a0, a1);
      float d = dis[i];
      a0 *= d; a1 *= d;
      if (l32 == 0) outY[o] = (float)y[i];
    }
    rows[r][2 * l32] = a0;
    rows[r][2 * l32 + 1] = a1;
  }
  __syncthreads();
  if (t < 64) {
    const int lane = t, quad = lane >> 4, m = lane & 15;
    float4v acc[4];
#pragma unroll
    for (int g = 0; g < 4; ++g) acc[g] = (float4v){0.f, 0.f, 0.f, 0.f};
#pragma unroll
    for (int k0 = 0; k0 < 2; ++k0) {
      short8 af;
#pragma unroll
      for (int j = 0; j < 8; ++j) af[j] = (short)f2bf(rows[m][k0 * 32 + quad * 8 + j]);
#pragma unroll
      for (int g = 0; g < 4; ++g) {
        short8 bf = *(const short8*)(packW2 + (((size_t)(g * 2 + k0) * 64 + lane) << 3));
        acc[g] = __builtin_amdgcn_mfma_f32_16x16x32_bf16(af, bf, acc[g], 0, 0, 0);
      }
    }
#pragma unroll
    for (int g = 0; g < 4; ++g) {
      float b = b2[g * 16 + m];
#pragma unroll
      for (int reg = 0; reg < 4; ++reg) {
        int r = quad * 4 + reg;
        if (ob + r < M) out0[(size_t)(ob + r) * 64 + g * 16 + m] = acc[g][reg] + b;
      }
    }
  }
}

extern "C" void kernel_launch(void* const* d_in, const int* in_sizes, int n_in,
                              void* d_out, int out_size, void* d_ws, size_t ws_size,
                              hipStream_t stream) {
  const float* doc   = (const float*)d_in[0];
  const float* wordf = (const float*)d_in[1];
  const float* ew    = (const float*)d_in[2];
  const float* Wlin  = (const float*)d_in[3];
  const float* blin  = (const float*)d_in[4];
  const float* W1    = (const float*)d_in[5];
  const float* b1    = (const float*)d_in[6];
  const float* W2    = (const float*)d_in[7];
  const float* b2    = (const float*)d_in[8];
  const int*   ei    = (const int*)d_in[9];
  const int*   mask  = (const int*)d_in[10];
  const int*   y     = (const int*)d_in[11];

  const int E  = in_sizes[2];
  const int M  = in_sizes[10];
  const int ND = in_sizes[0] / 768;
  const int NW = in_sizes[1] / 300;
  const int N  = ND + NW;
  const int NE = N + E;
  const int nbuck = (N + 255) >> 8;          // <= 512 (N <= 131072)

  // workspace carve (aligned 256B)
  char* p = (char*)d_ws;
  auto carve = [&](size_t bytes) -> void* {
    void* q = (void*)p;
    p += (bytes + 255) & ~(size_t)255;
    return q;
  };
  unsigned short* packW1 = (unsigned short*)carve((size_t)4 * 24 * 64 * 8 * 2);
  unsigned short* packW2 = (unsigned short*)carve((size_t)4 * 2 * 64 * 8 * 2);
  unsigned short* packWf = (unsigned short*)carve((size_t)4 * 10 * 64 * 8 * 2);
  float* bfuse     = (float*)carve(64 * 4);
  float* dis       = (float*)carve((size_t)N * 4);
  int*   offs      = (int*)carve(((size_t)N + 1) * 4);
  int*   bucketTot = (int*)carve((size_t)(nbuck + 2) * 4);
  int*   runInc    = (int*)carve((size_t)(nbuck + 2) * 4);
  int2*  ebuf      = (int2*)carve((size_t)E * 8);
  int2*  entries   = (int2*)carve((size_t)NE * 8);
  unsigned short* xw1 = (unsigned short*)carve((size_t)N * 64 * 2);  // bf16, permuted
  unsigned short* h1  = (unsigned short*)carve((size_t)N * 64 * 2);  // bf16, permuted

  // pack W1 + W2 + zero bucketTot/runInc/packWf-tail
  k_pack<<<27, 256, 0, stream>>>(W1, packW1, W2, packW2, bucketTot, runInc, nbuck, packWf);

  // k_pre: bucket hist || fuse MFMA (FUSEOUT -> packWf+bfuse) || doc MFMA
  const int fuseBlocks = (301 + 63) / 64;
  const int docBlocks  = (ND + 63) / 64;
  const int histBlocks = (E + 4095) / 4096;
  k_pre<<<histBlocks + fuseBlocks + docBlocks, 256, 0, stream>>>(
      Wlin, blin, packW1, packWf, bfuse, histBlocks, fuseBlocks,
      ei, E, bucketTot, nbuck, doc, xw1, ND);

  // word GEMM split 50/50 between k_sd and k_bw (rows are independent)
  const int wordBlocks = (NW + 63) / 64;
  const int wsdBlocks  = wordBlocks / 2;
  const int wsdRows    = wsdBlocks * 64;
  unsigned short* xw1word = xw1 + (size_t)ND * 64;

  // scatter (+local scan) || word GEMM rows [0, wsdRows)
  k_sd<<<histBlocks + wsdBlocks, 256, 0, stream>>>(
      ei, ew, E, histBlocks, bucketTot, nbuck, runInc, ebuf,
      wordf, packWf, bfuse, xw1word, wsdRows);

  // per-bucket CSR build (+local scan) || word GEMM rows [wsdRows, NW)
  k_bw<<<nbuck + (wordBlocks - wsdBlocks), 256, 0, stream>>>(
      ebuf, bucketTot, nbuck, N, offs, dis, entries,
      wordf + (size_t)wsdRows * 300, packWf, bfuse,
      xw1word + (size_t)wsdRows * 64, NW - wsdRows);

  // layer-1 aggregation (+b1 via pi, relu) -> bf16 h1 (permuted)
  k_agg<<<(N + 7) / 8, 256, 0, stream>>>(xw1, entries, offs, dis, b1, h1, N);

  // fused masked layer-2 aggregation + @W2 projection -> d_out
  float* out0 = (float*)d_out;
  float* outY = out0 + (size_t)M * 64;
  k_out<<<(M + 15) / 16, 256, 0, stream>>>(
      h1, entries, offs, dis, mask, y, packW2, b2, out0, outY, M);
}

// Round 10
// 314.710 us; speedup vs baseline: 1.0117x; 1.0117x over previous
//
#include <hip/hip_runtime.h>

// ---------------------------------------------------------------------------
// TextGCN (2-layer GCN, eval mode) on MI355X.
// Fusions:
//   * xw1_word = word @ (W_lin@W1) + (b_lin@W1)  (never materialize [N,768] x)
//   * layer 2: agg(h1@W2)[mask] == agg(h1)[mask] @ W2
// CSR BUILD = 2-LEVEL BUCKET SORT (no scattered-megaop atomics, r3 measured).
// GEMM: 16 rows/wave, CHUNK-deep A-load hoist, B always packed bf16 (r5/r6).
//   r9: word CHUNK=10 (single HBM stall-group/wave, 320B/lane in flight),
//   doc/fuse CHUNK=12 (2 groups). VGPR cost is FREE: these grids are
//   grid-limited (word ~10 waves/CU, doc ~5), occupancy tier unaffected.
// CHAIN (r8): 6 launches, 0 memsets; fuse GEMM writes packWf fragments
//   directly; bucket scan recomputed per-block in LDS; k_out fuses masked
//   agg + @W2 projection (tmask deleted).
// PIPELINE:
//   k_pack(packW1||packW2||zero{bucketTot,runInc,packWf tail}) ->
//   k_pre(bucketHist || fuseGEMM->packWf,bfuse || docGEMM) ->
//   k_sd(scatter+scan || wordGEMM rows[0,half)) ->
//   k_bw(bucketBuild+scan || wordGEMM rows[half,NW)) ->
//   k_agg -> k_out(masked agg + @W2 projection)
// xw1/h1 bf16 in PERMUTED column order pi(pos)=(pos&3)*16+(pos>>2) (coalesced
// 8B MFMA epilogue stores). b1 indexed via pi; packW2 k-rows permuted via pi.
// ebuf record: {src | (dst&255)<<17, w}  (src < 2^17 since N <= 131072).
// Fixed cost: harness re-poisons 384MB ws (~57us/iter @85% HBM peak).
// ---------------------------------------------------------------------------

typedef __attribute__((ext_vector_type(8))) short short8;   // 8 bf16 = 4 VGPR
typedef __attribute__((ext_vector_type(4))) float float4v;  // MFMA C/D frag

__device__ __forceinline__ unsigned short f2bf(float f) {   // RNE f32->bf16
  unsigned u = __float_as_uint(f);
  return (unsigned short)((u + 0x7FFFu + ((u >> 16) & 1u)) >> 16);
}
__device__ __forceinline__ float bf2f(unsigned short u) {
  return __uint_as_float((unsigned)u << 16);
}
__device__ __forceinline__ int permcol(int p) {   // pi: pos -> true col
  return ((p & 3) << 4) | (p >> 2);
}

// pack W[K,64] fp32 -> bf16 fragment order: pack[((g*nk0+k0)*64+lane)*8+j]
// holds W[ksrc][(lane&15)+16g], ksrc = PERM ? pi(k) : k; zero past K.
template <bool PERM>
__device__ __forceinline__ void pack_w_body(const float* __restrict__ W, int K,
                                            int nk0, unsigned short* __restrict__ pack,
                                            int tid) {
  int lane = tid & 63;
  int rest = tid >> 6;
  int k0 = rest % nk0;
  int g = rest / nk0;
  int quad = lane >> 4;
  int n = (lane & 15) + g * 16;
  short8 v;
#pragma unroll
  for (int j = 0; j < 8; ++j) {
    int k = k0 * 32 + quad * 8 + j;
    int ks = PERM ? permcol(k) : k;
    float w = (k < K) ? W[(size_t)ks * 64 + n] : 0.f;
    v[j] = (short)f2bf(w);
  }
  *(short8*)(pack + (((size_t)(g * nk0 + k0) * 64 + lane) << 3)) = v;
}

// MFMA GEMM: out[R,64] = X[R,K(ldx)] @ W[K,64] (+bias). One wave = 16 rows.
// NK0/CHUNK compile-time: A-loads for CHUNK k0s issued back-to-back (deep
// MLP), then convert+MFMA (compiler's counted vmcnt overlaps early MFMAs
// with late loads). B from packed bf16 fragments (L2-hot).
// FUSEOUT: epilogue writes packWf fragments (nk0=10 layout, rows<300) and
// bfuseOut fp32 (row 300) instead of a normal output matrix.
template <bool LAST, bool BF16PERM, bool FUSEOUT, int NK0, int CHUNK>
__device__ __forceinline__ void mfma_gemm_body(
    const float* __restrict__ X, int ldx, const float* __restrict__ lastRow,
    const unsigned short* __restrict__ Wpack,
    int K, const float* __restrict__ bias,
    void* __restrict__ outv, int R, int waveIdx, float* __restrict__ bfuseOut) {
  int r0 = waveIdx * 16;
  if (r0 >= R) return;
  const int lane = threadIdx.x & 63;
  const int quad = lane >> 4;
  const int m = lane & 15;
  const float* xrow = nullptr;
  {
    int row = r0 + m;
    if (row < R) xrow = (LAST && row == R - 1) ? lastRow : X + (size_t)row * ldx;
  }

  float4v acc[4];
#pragma unroll
  for (int g = 0; g < 4; ++g) acc[g] = (float4v){0.f, 0.f, 0.f, 0.f};

#pragma unroll
  for (int c0 = 0; c0 < NK0; c0 += CHUNK) {
    // ---- A-hoist: all CHUNK k0 loads, no dependent compute between ----
    float a[CHUNK][8];
#pragma unroll
    for (int cc = 0; cc < CHUNK; ++cc) {
      int kb = (c0 + cc) * 32 + quad * 8;
      if (xrow && kb + 8 <= K) {
        float4 v0 = *(const float4*)(xrow + kb);
        float4 v1 = *(const float4*)(xrow + kb + 4);
        a[cc][0] = v0.x; a[cc][1] = v0.y; a[cc][2] = v0.z; a[cc][3] = v0.w;
        a[cc][4] = v1.x; a[cc][5] = v1.y; a[cc][6] = v1.z; a[cc][7] = v1.w;
      } else {
#pragma unroll
        for (int j = 0; j < 8; ++j) {
          int k = kb + j;
          a[cc][j] = (xrow && k < K) ? xrow[k] : 0.f;
        }
      }
    }
    // ---- compute the chunk (packed bf16 B fragments) ----
#pragma unroll
    for (int cc = 0; cc < CHUNK; ++cc) {
      int k0 = c0 + cc;
      short8 bf[4];
#pragma unroll
      for (int g = 0; g < 4; ++g)
        bf[g] = *(const short8*)(Wpack + (((size_t)(g * NK0 + k0) * 64 + lane) << 3));
      short8 af;
#pragma unroll
      for (int j = 0; j < 8; ++j) af[j] = (short)f2bf(a[cc][j]);
#pragma unroll
      for (int g = 0; g < 4; ++g)
        acc[g] = __builtin_amdgcn_mfma_f32_16x16x32_bf16(af, bf[g], acc[g], 0, 0, 0);
    }
  }

  // ---- epilogue ----
  if (FUSEOUT) {
    // write packWf fragments (nk0=10): element (k=r, n=c) ->
    // pack[((g*10 + r/32)*64 + ((r%32)/8)*16 + m)*8 + r%8]
    unsigned short* pf = (unsigned short*)outv;
#pragma unroll
    for (int g = 0; g < 4; ++g) {
#pragma unroll
      for (int reg = 0; reg < 4; ++reg) {
        int r = r0 + quad * 4 + reg;
        if (r < 300) {
          size_t idx = ((((size_t)(g * 10 + (r >> 5))) * 64 + (((r >> 3) & 3) << 4) + m) << 3)
                       + (r & 7);
          pf[idx] = f2bf(acc[g][reg]);
        } else if (r == 300) {
          bfuseOut[g * 16 + m] = acc[g][reg];
        }
      }
    }
  } else if (BF16PERM) {
    // lane m packs cols {m,16+m,32+m,48+m} of row r0+quad*4+j as 4 bf16 (8B)
    float b0 = bias ? bias[m] : 0.f;
    float b1 = bias ? bias[16 + m] : 0.f;
    float b2 = bias ? bias[32 + m] : 0.f;
    float b3 = bias ? bias[48 + m] : 0.f;
#pragma unroll
    for (int j = 0; j < 4; ++j) {
      int r = r0 + quad * 4 + j;
      if (r < R) {
        ushort4 pk;
        pk.x = f2bf(acc[0][j] + b0);
        pk.y = f2bf(acc[1][j] + b1);
        pk.z = f2bf(acc[2][j] + b2);
        pk.w = f2bf(acc[3][j] + b3);
        *(ushort4*)((unsigned short*)outv + ((size_t)r * 64 + m * 4)) = pk;
      }
    }
  } else {
#pragma unroll
    for (int g = 0; g < 4; ++g) {
      float b = bias ? bias[g * 16 + m] : 0.f;
#pragma unroll
      for (int reg = 0; reg < 4; ++reg) {
        int r = r0 + quad * 4 + reg;   // C/D: col=lane&15, row=quad*4+reg
        if (r < R) ((float*)outv)[(size_t)r * 64 + g * 16 + m] = acc[g][reg] + b;
      }
    }
  }
}

// k_pack: [24) pack W1; [+2) pack W2 (permuted k);
//         [+1) zero bucketTot + runInc + packWf k0=9 tail (k=288..319).
__global__ __launch_bounds__(256) void k_pack(
    const float* __restrict__ W1, unsigned short* __restrict__ packW1,
    const float* __restrict__ W2, unsigned short* __restrict__ packW2,
    int* __restrict__ bucketTot, int* __restrict__ runInc, int nbuck,
    unsigned short* __restrict__ packWf) {
  int b = blockIdx.x;
  int t = threadIdx.x;
  if (b < 24) { pack_w_body<false>(W1, 768, 24, packW1, b * 256 + t); return; }
  b -= 24;
  if (b < 2) { pack_w_body<true>(W2, 64, 2, packW2, b * 256 + t); return; }
  for (int i = t; i < nbuck + 2; i += 256) { bucketTot[i] = 0; runInc[i] = 0; }
  // zero packWf k0=9 fragments (fuse epilogue fills k=288..299; 300..319 = 0)
  int g = t >> 6, lane = t & 63;
  *(short8*)(packWf + (((size_t)(g * 10 + 9) * 64 + lane) << 3)) = (short8){0,0,0,0,0,0,0,0};
}

// k_pre: [histBlocks) bucket histogram (LDS, flush <=nbuck atomics/block);
//        [+fuseBlocks) fuse GEMM [Wlin;blin]@W1 -> packWf + bfuse (FUSEOUT);
//        rest: doc GEMM (packed W1) -> xw1 rows [0,ND).
__global__ __launch_bounds__(256) void k_pre(
    const float* __restrict__ Wlin, const float* __restrict__ blin,
    const unsigned short* __restrict__ packW1,
    unsigned short* __restrict__ packWf, float* __restrict__ bfuse,
    int histBlocks, int fuseBlocks,
    const int* __restrict__ ei, int E, int* __restrict__ bucketTot, int nbuck,
    const float* __restrict__ doc, unsigned short* __restrict__ xw1, int ND) {
  int b = blockIdx.x;
  int t = threadIdx.x;
  if (b < histBlocks) {
    __shared__ int h[512];
    h[t] = 0; h[t + 256] = 0;
    __syncthreads();
    int e0 = b * 4096;
#pragma unroll 4
    for (int i = 0; i < 16; ++i) {
      int e = e0 + t + i * 256;
      if (e < E) atomicAdd(&h[ei[E + e] >> 8], 1);
    }
    __syncthreads();
    if (t < nbuck && h[t]) atomicAdd(bucketTot + t, h[t]);
    if (t + 256 < nbuck && h[t + 256]) atomicAdd(bucketTot + t + 256, h[t + 256]);
    return;
  }
  b -= histBlocks;
  if (b < fuseBlocks) {
    mfma_gemm_body<true, false, true, 24, 12>(Wlin, 768, blin, packW1, 768,
                                              nullptr, packWf, 301, b * 4 + (t >> 6), bfuse);
    return;
  }
  b -= fuseBlocks;
  mfma_gemm_body<false, true, false, 24, 12>(doc, 768, nullptr, packW1, 768,
                                             nullptr, xw1, ND, b * 4 + (t >> 6), nullptr);
}

// in-block bucket prefix scan: bb[0..512] exclusive bases from bucketTot.
// 256 threads, pair-load + Hillis-Steele. Caller provides LDS arrays.
__device__ __forceinline__ void bucket_scan(const int* __restrict__ bucketTot, int nbuck,
                                            int* __restrict__ sc, int* __restrict__ bb,
                                            int t) {
  int a0 = (2 * t < nbuck) ? bucketTot[2 * t] : 0;
  int a1 = (2 * t + 1 < nbuck) ? bucketTot[2 * t + 1] : 0;
  sc[t] = a0 + a1;
  __syncthreads();
  for (int off = 1; off < 256; off <<= 1) {
    int x = (t >= off) ? sc[t - off] : 0;
    __syncthreads();
    sc[t] += x;
    __syncthreads();
  }
  int pe = sc[t] - a0 - a1;
  bb[2 * t] = pe;
  bb[2 * t + 1] = pe + a0;
  if (t == 255) bb[512] = sc[255];
  __syncthreads();
}

// k_sd: [scatBlocks) scatter edges into bucket-grouped ebuf (LDS hist+rank,
// run reservation = local bucket base + atomicAdd(runInc)); rest: word GEMM
// rows [0, NWsd) (packed WfuseB fragments).
__global__ __launch_bounds__(256) void k_sd(
    const int* __restrict__ ei, const float* __restrict__ ew, int E,
    int scatBlocks, const int* __restrict__ bucketTot, int nbuck,
    int* __restrict__ runInc, int2* __restrict__ ebuf,
    const float* __restrict__ wordf, const unsigned short* __restrict__ packWf,
    const float* __restrict__ bfuse, unsigned short* __restrict__ xw1word, int NWsd) {
  int b = blockIdx.x;
  int t = threadIdx.x;
  if (b >= scatBlocks) {
    mfma_gemm_body<false, true, false, 10, 10>(wordf, 300, nullptr, packWf, 300,
                                               bfuse, xw1word, NWsd,
                                               (b - scatBlocks) * 4 + (t >> 6), nullptr);
    return;
  }
  __shared__ int h[512];
  __shared__ int base[512];
  __shared__ int cur[512];
  __shared__ int bb[513];
  __shared__ int sc[256];
  h[t] = 0; h[t + 256] = 0;
  __syncthreads();
  int e0 = b * 4096;
#pragma unroll 4
  for (int i = 0; i < 16; ++i) {
    int e = e0 + t + i * 256;
    if (e < E) atomicAdd(&h[ei[E + e] >> 8], 1);
  }
  __syncthreads();
  bucket_scan(bucketTot, nbuck, sc, bb, t);   // also covers hist completion
#pragma unroll
  for (int k = t; k < 512; k += 256) {
    if (h[k]) base[k] = bb[k] + atomicAdd(runInc + k, h[k]);
    cur[k] = 0;
  }
  __syncthreads();
#pragma unroll 4
  for (int i = 0; i < 16; ++i) {
    int e = e0 + t + i * 256;
    if (e < E) {
      int d = ei[E + e];
      int bk = d >> 8;
      int r = base[bk] + atomicAdd(&cur[bk], 1);
      ebuf[r] = make_int2(ei[e] | ((d & 255) << 17), __float_as_int(ew[e]));
    }
  }
}

// k_bw: [nbuck) per-bucket CSR build (local scan -> estart/eend; LDS
// cnt/wdeg/scan -> contiguous entries slice + offs + dis); rest: word GEMM
// rows [NWsd, NW) via pre-offset pointers.
__global__ __launch_bounds__(256) void k_bw(
    const int2* __restrict__ ebuf, const int* __restrict__ bucketTot,
    int nbuck, int N, int* __restrict__ offs, float* __restrict__ dis,
    int2* __restrict__ entries,
    const float* __restrict__ wordf2, const unsigned short* __restrict__ packWf,
    const float* __restrict__ bfuse, unsigned short* __restrict__ xw1word2, int NW2) {
  int b = blockIdx.x;
  int t = threadIdx.x;
  if (b >= nbuck) {
    mfma_gemm_body<false, true, false, 10, 10>(wordf2, 300, nullptr, packWf, 300,
                                               bfuse, xw1word2, NW2,
                                               (b - nbuck) * 4 + (t >> 6), nullptr);
    return;
  }
  __shared__ int scnt[256];
  __shared__ float swd[256];
  __shared__ int sscan[256];
  __shared__ int scur[256];
  __shared__ int bb[513];
  __shared__ int sc[256];
  bucket_scan(bucketTot, nbuck, sc, bb, t);
  int estart = bb[b], eend = bb[b + 1];
  int node0 = b << 8;
  int nn = min(256, N - node0);
  scnt[t] = (t < nn) ? 1 : 0;          // self loop
  swd[t] = (t < nn) ? 1.f : 0.f;       // self weight
  __syncthreads();
  for (int p = estart + t; p < eend; p += 256) {
    int2 e = ebuf[p];
    int low = (e.x >> 17) & 255;
    atomicAdd(&scnt[low], 1);
    atomicAdd(&swd[low], __int_as_float(e.y));
  }
  __syncthreads();
  int v = scnt[t];
  sscan[t] = v; __syncthreads();
  for (int off = 1; off < 256; off <<= 1) {
    int x = (t >= off) ? sscan[t - off] : 0;
    __syncthreads();
    sscan[t] += x;
    __syncthreads();
  }
  int excl = sscan[t] - v;
  int entriesBase = estart + node0;    // edges-before + selfs-before
  if (t < nn) {
    offs[node0 + t] = entriesBase + excl;
    dis[node0 + t] = rsqrtf(fmaxf(swd[t], 1e-12f));
    entries[entriesBase + excl] = make_int2(node0 + t, __float_as_int(1.0f));
  }
  scur[t] = excl + 1;
  if (t == 0 && b == nbuck - 1) offs[N] = entriesBase + (eend - estart) + nn;
  __syncthreads();
  for (int p = estart + t; p < eend; p += 256) {
    int2 e = ebuf[p];
    int low = (e.x >> 17) & 255;
    int r = atomicAdd(&scur[low], 1);
    entries[entriesBase + r] = make_int2(e.x & 0x1FFFF, e.y);
  }
}

// half-wave gather-accumulate: 32 lanes, each lane covers 2 cols (ushort2).
// entries hold RAW w -> multiply dis[src] per entry (broadcast, L2-hot).
__device__ __forceinline__ void row_gather2(const unsigned short* __restrict__ xin,
                                            const int2* __restrict__ entries,
                                            const float* __restrict__ dis,
                                            int p, int pe, int l32,
                                            float& ra0, float& ra1) {
  float a0 = 0.f, a1 = 0.f;
  for (; p + 8 <= pe; p += 8) {
    int2 e[8];
#pragma unroll
    for (int j = 0; j < 8; ++j) e[j] = entries[p + j];
    unsigned x[8];
    float ds[8];
#pragma unroll
    for (int j = 0; j < 8; ++j) {
      x[j] = *(const unsigned*)(xin + ((size_t)e[j].x << 6) + (l32 << 1));
      ds[j] = dis[e[j].x];
    }
#pragma unroll
    for (int j = 0; j < 8; ++j) {
      float w = __int_as_float(e[j].y) * ds[j];
      a0 = fmaf(bf2f((unsigned short)(x[j] & 0xffffu)), w, a0);
      a1 = fmaf(bf2f((unsigned short)(x[j] >> 16)), w, a1);
    }
  }
  if (p + 4 <= pe) {
    int2 e[4];
#pragma unroll
    for (int j = 0; j < 4; ++j) e[j] = entries[p + j];
    unsigned x[4];
    float ds[4];
#pragma unroll
    for (int j = 0; j < 4; ++j) {
      x[j] = *(const unsigned*)(xin + ((size_t)e[j].x << 6) + (l32 << 1));
      ds[j] = dis[e[j].x];
    }
#pragma unroll
    for (int j = 0; j < 4; ++j) {
      float w = __int_as_float(e[j].y) * ds[j];
      a0 = fmaf(bf2f((unsigned short)(x[j] & 0xffffu)), w, a0);
      a1 = fmaf(bf2f((unsigned short)(x[j] >> 16)), w, a1);
    }
    p += 4;
  }
  for (; p < pe; ++p) {
    int2 e = entries[p];
    unsigned x = *(const unsigned*)(xin + ((size_t)e.x << 6) + (l32 << 1));
    float w = __int_as_float(e.y) * dis[e.x];
    a0 = fmaf(bf2f((unsigned short)(x & 0xffffu)), w, a0);
    a1 = fmaf(bf2f((unsigned short)(x >> 16)), w, a1);
  }
  ra0 = a0; ra1 = a1;
}

// layer-1 aggregation: half-wave per node, ushort2 out (permuted pos layout)
__global__ void k_agg(const unsigned short* __restrict__ xin, const int2* __restrict__ entries,
                      const int* __restrict__ offs, const float* __restrict__ dis,
                      const float* __restrict__ bias, unsigned short* __restrict__ xout, int N) {
  const int tid = threadIdx.x;
  const int l32 = tid & 31;
  int i = blockIdx.x * 8 + (tid >> 5);
  if (i >= N) return;
  float a0, a1;
  row_gather2(xin, entries, dis, offs[i], offs[i + 1], l32, a0, a1);
  float d = dis[i];
  a0 = fmaxf(fmaf(a0, d, bias[permcol(2 * l32)]), 0.f);
  a1 = fmaxf(fmaf(a1, d, bias[permcol(2 * l32 + 1)]), 0.f);
  ushort2 pk;
  pk.x = f2bf(a0);
  pk.y = f2bf(a1);
  *(ushort2*)(xout + ((size_t)i << 6) + (l32 << 1)) = pk;
}

// k_out: fused masked layer-2 aggregation + [16,64]@[64,64]+b2 projection.
// Block = 16 masked nodes: 8 half-waves x 2 rounds gather into LDS rows
// (pos order, pad 65 -> 2-way banks = free), then wave 0 MFMAs with
// permuted-k packW2 and writes fp32 out. outY written during gather.
__global__ __launch_bounds__(256) void k_out(
    const unsigned short* __restrict__ h1, const int2* __restrict__ entries,
    const int* __restrict__ offs, const float* __restrict__ dis,
    const int* __restrict__ mask, const int* __restrict__ y,
    const unsigned short* __restrict__ packW2, const float* __restrict__ b2,
    float* __restrict__ out0, float* __restrict__ outY, int M) {
  __shared__ float rows[16][65];
  const int t = threadIdx.x;
  const int l32 = t & 31;
  const int hw = t >> 5;
  const int ob = blockIdx.x * 16;
#pragma unroll
  for (int rd = 0; rd < 2; ++rd) {
    int r = rd * 8 + hw;
    int o = ob + r;
    float a0 = 0.f, a1 = 0.f;
    if (o < M) {
      int i = mask[o];
      row_gather2(h1, entries, dis, offs[i], offs[i + 1], l32, a0, a1);
      float d = dis[i];
      a0 *= d; a1 *= d;
      if (l32 == 0) outY[o] = (float)y[i];
    }
    rows[r][2 * l32] = a0;
    rows[r][2 * l32 + 1] = a1;
  }
  __syncthreads();
  if (t < 64) {
    const int lane = t, quad = lane >> 4, m = lane & 15;
    float4v acc[4];
#pragma unroll
    for (int g = 0; g < 4; ++g) acc[g] = (float4v){0.f, 0.f, 0.f, 0.f};
#pragma unroll
    for (int k0 = 0; k0 < 2; ++k0) {
      short8 af;
#pragma unroll
      for (int j = 0; j < 8; ++j) af[j] = (short)f2bf(rows[m][k0 * 32 + quad * 8 + j]);
#pragma unroll
      for (int g = 0; g < 4; ++g) {
        short8 bf = *(const short8*)(packW2 + (((size_t)(g * 2 + k0) * 64 + lane) << 3));
        acc[g] = __builtin_amdgcn_mfma_f32_16x16x32_bf16(af, bf, acc[g], 0, 0, 0);
      }
    }
#pragma unroll
    for (int g = 0; g < 4; ++g) {
      float b = b2[g * 16 + m];
#pragma unroll
      for (int reg = 0; reg < 4; ++reg) {
        int r = quad * 4 + reg;
        if (ob + r < M) out0[(size_t)(ob + r) * 64 + g * 16 + m] = acc[g][reg] + b;
      }
    }
  }
}

extern "C" void kernel_launch(void* const* d_in, const int* in_sizes, int n_in,
                              void* d_out, int out_size, void* d_ws, size_t ws_size,
                              hipStream_t stream) {
  const float* doc   = (const float*)d_in[0];
  const float* wordf = (const float*)d_in[1];
  const float* ew    = (const float*)d_in[2];
  const float* Wlin  = (const float*)d_in[3];
  const float* blin  = (const float*)d_in[4];
  const float* W1    = (const float*)d_in[5];
  const float* b1    = (const float*)d_in[6];
  const float* W2    = (const float*)d_in[7];
  const float* b2    = (const float*)d_in[8];
  const int*   ei    = (const int*)d_in[9];
  const int*   mask  = (const int*)d_in[10];
  const int*   y     = (const int*)d_in[11];

  const int E  = in_sizes[2];
  const int M  = in_sizes[10];
  const int ND = in_sizes[0] / 768;
  const int NW = in_sizes[1] / 300;
  const int N  = ND + NW;
  const int NE = N + E;
  const int nbuck = (N + 255) >> 8;          // <= 512 (N <= 131072)

  // workspace carve (aligned 256B)
  char* p = (char*)d_ws;
  auto carve = [&](size_t bytes) -> void* {
    void* q = (void*)p;
    p += (bytes + 255) & ~(size_t)255;
    return q;
  };
  unsigned short* packW1 = (unsigned short*)carve((size_t)4 * 24 * 64 * 8 * 2);
  unsigned short* packW2 = (unsigned short*)carve((size_t)4 * 2 * 64 * 8 * 2);
  unsigned short* packWf = (unsigned short*)carve((size_t)4 * 10 * 64 * 8 * 2);
  float* bfuse     = (float*)carve(64 * 4);
  float* dis       = (float*)carve((size_t)N * 4);
  int*   offs      = (int*)carve(((size_t)N + 1) * 4);
  int*   bucketTot = (int*)carve((size_t)(nbuck + 2) * 4);
  int*   runInc    = (int*)carve((size_t)(nbuck + 2) * 4);
  int2*  ebuf      = (int2*)carve((size_t)E * 8);
  int2*  entries   = (int2*)carve((size_t)NE * 8);
  unsigned short* xw1 = (unsigned short*)carve((size_t)N * 64 * 2);  // bf16, permuted
  unsigned short* h1  = (unsigned short*)carve((size_t)N * 64 * 2);  // bf16, permuted

  // pack W1 + W2 + zero bucketTot/runInc/packWf-tail
  k_pack<<<27, 256, 0, stream>>>(W1, packW1, W2, packW2, bucketTot, runInc, nbuck, packWf);

  // k_pre: bucket hist || fuse MFMA (FUSEOUT -> packWf+bfuse) || doc MFMA
  const int fuseBlocks = (301 + 63) / 64;
  const int docBlocks  = (ND + 63) / 64;
  const int histBlocks = (E + 4095) / 4096;
  k_pre<<<histBlocks + fuseBlocks + docBlocks, 256, 0, stream>>>(
      Wlin, blin, packW1, packWf, bfuse, histBlocks, fuseBlocks,
      ei, E, bucketTot, nbuck, doc, xw1, ND);

  // word GEMM split 50/50 between k_sd and k_bw (rows are independent)
  const int wordBlocks = (NW + 63) / 64;
  const int wsdBlocks  = wordBlocks / 2;
  const int wsdRows    = wsdBlocks * 64;
  unsigned short* xw1word = xw1 + (size_t)ND * 64;

  // scatter (+local scan) || word GEMM rows [0, wsdRows)
  k_sd<<<histBlocks + wsdBlocks, 256, 0, stream>>>(
      ei, ew, E, histBlocks, bucketTot, nbuck, runInc, ebuf,
      wordf, packWf, bfuse, xw1word, wsdRows);

  // per-bucket CSR build (+local scan) || word GEMM rows [wsdRows, NW)
  k_bw<<<nbuck + (wordBlocks - wsdBlocks), 256, 0, stream>>>(
      ebuf, bucketTot, nbuck, N, offs, dis, entries,
      wordf + (size_t)wsdRows * 300, packWf, bfuse,
      xw1word + (size_t)wsdRows * 64, NW - wsdRows);

  // layer-1 aggregation (+b1 via pi, relu) -> bf16 h1 (permuted)
  k_agg<<<(N + 7) / 8, 256, 0, stream>>>(xw1, entries, offs, dis, b1, h1, N);

  // fused masked layer-2 aggregation + @W2 projection -> d_out
  float* out0 = (float*)d_out;
  float* outY = out0 + (size_t)M * 64;
  k_out<<<(M + 15) / 16, 256, 0, stream>>>(
      h1, entries, offs, dis, mask, y, packW2, b2, out0, outY, M);
}